// Round 5
// baseline (753.689 us; speedup 1.0000x reference)
//
#include <hip/hip_runtime.h>

typedef _Float16 f16;
typedef _Float16 f16x8 __attribute__((ext_vector_type(8)));
typedef float f32x4 __attribute__((ext_vector_type(4)));

static __device__ __forceinline__ f32x4 mfma16(f16x8 a, f16x8 b, f32x4 c) {
  return __builtin_amdgcn_mfma_f32_16x16x32_f16(a, b, c, 0, 0, 0);
}

#define GLD16(gp, lp) __builtin_amdgcn_global_load_lds( \
    (const __attribute__((address_space(1))) unsigned int*)(gp), \
    (__attribute__((address_space(3))) unsigned int*)(lp), 16, 0, 0)

// ---------------- K0: weight prep (fp32 -> f16, transposed to [n][k]) ----------------
__global__ __launch_bounds__(256) void k0_prep(
    const float* __restrict__ W0, const float* __restrict__ b0,
    const float* __restrict__ W1, const float* __restrict__ b1,
    const float* __restrict__ W2, const float* __restrict__ b2,
    const float* __restrict__ W3, const float* __restrict__ b3,
    const float* __restrict__ Wf, const float* __restrict__ Ws,
    f16* __restrict__ wqkvT, f16* __restrict__ wfT, f16* __restrict__ wsT,
    float* __restrict__ bqkv)
{
  int t = blockIdx.x * 256 + threadIdx.x;
  if (t < 49152) {                       // wqkvT [384][128], n = h*96 + j
    int n = t >> 7, k = t & 127;
    int h = n / 96, nn = n - h * 96;
    const float* W = (h == 0) ? W0 : (h == 1) ? W1 : (h == 2) ? W2 : W3;
    wqkvT[t] = (f16)W[k * 96 + nn];
  } else if (t < 114688) {               // wfT [256][256]
    int i = t - 49152;
    int n = i >> 8, k = i & 255;
    wfT[i] = (f16)Wf[k * 256 + n];
  } else if (t < 901120) {               // wsT [256][3072]
    int i = t - 114688;
    int n = i / 3072, k = i - n * 3072;
    wsT[i] = (f16)Ws[k * 256 + n];
  } else if (t < 901504) {               // bqkv [384] fp32
    int i = t - 901120;
    int h = i / 96, j = i - h * 96;
    const float* bp = (h == 0) ? b0 : (h == 1) ? b1 : (h == 2) ? b2 : b3;
    bqkv[i] = bp[j];
  }
}

// ---------------- K1: fused qkv + attention + LN1 + Wf + LN2 -> f_norm (f16) ----------------
// 256 threads, LDS = 51 KB -> 3 blocks/CU. Weight-fragment loads (wqkvT/wfT)
// are register double-buffered (prefetch k+1 while MFMA on k) to hide L2
// latency; bias/LN-affine params hoisted to regs (per-thread cols are fixed).
#define RB 8            // batch rows per block
#define SR 48           // seq rows = RB*6
#define XP 136          // f16 pitch for 128-col x tile
#define QP 392          // f16 pitch for qkv (384 cols)

__global__ __launch_bounds__(256, 3) void k1_fused(
    const float* __restrict__ x,
    const f16* __restrict__ wqkvT, const f16* __restrict__ wfT,
    const float* __restrict__ bqkv,
    const float* __restrict__ g1, const float* __restrict__ be1,
    const float* __restrict__ bfv,
    const float* __restrict__ g2, const float* __restrict__ be2,
    f16* __restrict__ fbuf)
{
  __shared__ f16 xs[SR * XP];       // x tile (m cols 0..127 / f cols 256..383)
  __shared__ f16 qn[SR * QP];       // qkv; Q cols -> attn; K/V bands -> n -> nWf
  __shared__ float sum1[SR], sq1[SR], mu1[SR], rs1[SR];
  __shared__ float sum2[SR], sq2[SR], mu2[SR], rs2[SR];

  const int t = threadIdx.x;
  const int lane = t & 63, wave = t >> 6;   // 4 waves
  const int lr = lane & 15, lq = lane >> 4;
  const int b0r = blockIdx.x * RB;

  // ---- P0: stat zeroing ----
  if (t < SR) { sum1[t] = 0.f; sq1[t] = 0.f; sum2[t] = 0.f; sq2[t] = 0.f; }

  // ---- P1: load x -> xs (f16) ----
  {
    const float4* xg = (const float4*)(x + (size_t)b0r * 768);
    #pragma unroll
    for (int it = 0; it < 6; it++) {
      int i = t + it * 256;               // 0..1535 ; 32 float4 per row
      float4 v = xg[i];
      int r = i >> 5, c4 = i & 31;
      f16* d = &xs[r * XP + c4 * 4];
      d[0] = (f16)v.x; d[1] = (f16)v.y; d[2] = (f16)v.z; d[3] = (f16)v.w;
    }
  }
  __syncthreads();

  // ---- P2: qkv = x @ Wqkv + b  (MFMA M=48 N=384 K=128; B-frags reg-dbuf) ----
  {
    float bb[6];
    #pragma unroll
    for (int nt = 0; nt < 6; nt++) bb[nt] = bqkv[(wave * 6 + nt) * 16 + lr];
    f32x4 acc[3][6];
    #pragma unroll
    for (int mt = 0; mt < 3; mt++)
      #pragma unroll
      for (int nt = 0; nt < 6; nt++) acc[mt][nt] = (f32x4){0.f, 0.f, 0.f, 0.f};
    f16x8 bv[2][6];
    #pragma unroll
    for (int nt = 0; nt < 6; nt++)
      bv[0][nt] = *(const f16x8*)&wqkvT[((wave * 6 + nt) * 16 + lr) * 128 + lq * 8];
    #pragma unroll
    for (int kk = 0; kk < 4; kk++) {
      if (kk < 3) {
        #pragma unroll
        for (int nt = 0; nt < 6; nt++)
          bv[(kk + 1) & 1][nt] = *(const f16x8*)&wqkvT[((wave * 6 + nt) * 16 + lr) * 128
                                                       + (kk + 1) * 32 + lq * 8];
      }
      f16x8 av[3];
      #pragma unroll
      for (int mt = 0; mt < 3; mt++)
        av[mt] = *(const f16x8*)&xs[(mt * 16 + lr) * XP + kk * 32 + lq * 8];
      #pragma unroll
      for (int nt = 0; nt < 6; nt++)
        #pragma unroll
        for (int mt = 0; mt < 3; mt++)
          acc[mt][nt] = mfma16(av[mt], bv[kk & 1][nt], acc[mt][nt]);
    }
    #pragma unroll
    for (int nt = 0; nt < 6; nt++) {
      int c = (wave * 6 + nt) * 16 + lr;
      #pragma unroll
      for (int mt = 0; mt < 3; mt++) {
        #pragma unroll
        for (int rg = 0; rg < 4; rg++) {
          int r = mt * 16 + lq * 4 + rg;
          qn[r * QP + c] = (f16)(acc[mt][nt][rg] + bb[nt]);
        }
      }
    }
  }
  __syncthreads();

  // ---- P3: attention (VALU, fp32 accumulate). thread = (b, h, i).
  //      Output overwrites own Q band (race-free; Q row i is in this
  //      thread's regs before any write). ----
  if (t < 192) {
    int b = t / 24;
    int rem = t - b * 24;
    int h = rem / 6, i = rem - (rem / 6) * 6;
    const f16* base = &qn[(b * 6) * QP + h * 96];
    float q[32], o[32], s[6];
    {
      const f16x8* Qr = (const f16x8*)(base + i * QP);
      #pragma unroll
      for (int u = 0; u < 4; u++) {
        f16x8 v = Qr[u];
        #pragma unroll
        for (int e = 0; e < 8; e++) q[u * 8 + e] = (float)v[e];
      }
    }
    #pragma unroll
    for (int j = 0; j < 6; j++) {
      const f16x8* Kr = (const f16x8*)(base + j * QP + 32);
      float a = 0.f;
      #pragma unroll
      for (int u = 0; u < 4; u++) {
        f16x8 v = Kr[u];
        #pragma unroll
        for (int e = 0; e < 8; e++) a += q[u * 8 + e] * (float)v[e];
      }
      s[j] = a;
    }
    #pragma unroll
    for (int d = 0; d < 32; d++) o[d] = 0.f;
    #pragma unroll
    for (int j = 0; j < 6; j++) {
      const f16x8* Vr = (const f16x8*)(base + j * QP + 64);
      float sj = s[j];
      #pragma unroll
      for (int u = 0; u < 4; u++) {
        f16x8 v = Vr[u];
        #pragma unroll
        for (int e = 0; e < 8; e++) o[u * 8 + e] += sj * (float)v[e];
      }
    }
    f16x8* Ar = (f16x8*)&qn[(b * 6 + i) * QP + h * 96];   // overwrite own Q band
    #pragma unroll
    for (int u = 0; u < 4; u++) {
      f16x8 v;
      #pragma unroll
      for (int e = 0; e < 8; e++) v[e] = (f16)o[u * 8 + e];
      Ar[u] = v;
    }
  }
  __syncthreads();

  // ---- P4: LN1 stats over m = [xs | attn(Q bands)] (256 cols) ----
  // P5 affine params: cols (t&15)*16 are per-thread constant -> hoist loads
  // here so latency hides behind the stats barrier.
  float g1v[16], b1v[16];
  {
    const int c5 = (t & 15) * 16;
    #pragma unroll
    for (int u = 0; u < 4; u++) {
      float4 a = *(const float4*)(g1 + c5 + u * 4);
      float4 b = *(const float4*)(be1 + c5 + u * 4);
      g1v[u*4+0]=a.x; g1v[u*4+1]=a.y; g1v[u*4+2]=a.z; g1v[u*4+3]=a.w;
      b1v[u*4+0]=b.x; b1v[u*4+1]=b.y; b1v[u*4+2]=b.z; b1v[u*4+3]=b.w;
    }
  }
  if (t < 192) {
    int r = t >> 2, qq = t & 3;
    float s = 0.f, ss = 0.f;
    if (qq < 2) {
      const f16x8* src = (const f16x8*)&xs[r * XP + qq * 64];
      #pragma unroll
      for (int u = 0; u < 8; u++) {
        f16x8 v = src[u];
        #pragma unroll
        for (int e = 0; e < 8; e++) { float f = (float)v[e]; s += f; ss += f * f; }
      }
    } else {
      int h0 = (qq - 2) * 2;              // heads h0, h0+1 (32 cols each)
      const f16x8* s0 = (const f16x8*)&qn[r * QP + h0 * 96];
      const f16x8* s1 = (const f16x8*)&qn[r * QP + (h0 + 1) * 96];
      #pragma unroll
      for (int u = 0; u < 4; u++) {
        f16x8 v = s0[u];
        #pragma unroll
        for (int e = 0; e < 8; e++) { float f = (float)v[e]; s += f; ss += f * f; }
      }
      #pragma unroll
      for (int u = 0; u < 4; u++) {
        f16x8 v = s1[u];
        #pragma unroll
        for (int e = 0; e < 8; e++) { float f = (float)v[e]; s += f; ss += f * f; }
      }
    }
    atomicAdd(&sum1[r], s);
    atomicAdd(&sq1[r], ss);
  }
  __syncthreads();
  if (t < SR) {
    float mu = sum1[t] * (1.f / 256.f);
    float var = sq1[t] * (1.f / 256.f) - mu * mu;
    mu1[t] = mu; rs1[t] = rsqrtf(var + 1e-5f);
  }
  __syncthreads();

  // ---- P5: n = LN1(m)*g1+be1 -> K/V bands of qn (band = c0>>6, at 32+band*96) ----
  {
    const int c0 = (t & 15) * 16;         // per-thread constant cols
    #pragma unroll
    for (int it = 0; it < 3; it++) {
      int i = t + it * 256;               // 0..767
      int r = i >> 4;
      float mu = mu1[r], rs = rs1[r];
      const f16* src = (c0 < 128)
          ? &xs[r * XP + c0]
          : &qn[r * QP + ((c0 - 128) >> 5) * 96 + ((c0 - 128) & 31)];
      f16x8 ov[2];
      #pragma unroll
      for (int u = 0; u < 2; u++) {
        f16x8 v = ((const f16x8*)src)[u];
        #pragma unroll
        for (int e = 0; e < 8; e++) {
          int idx = u * 8 + e;
          ov[u][e] = (f16)(((float)v[e] - mu) * rs * g1v[idx] + b1v[idx]);
        }
      }
      f16x8* dst = (f16x8*)&qn[r * QP + 32 + (c0 >> 6) * 96 + (c0 & 63)];
      dst[0] = ov[0]; dst[1] = ov[1];
    }
  }
  __syncthreads();

  // ---- P6: nWf = n @ Wf (MFMA M=48 N=256 K=256; B-frags reg-dbuf) ----
  float bbf[4];
  #pragma unroll
  for (int nt = 0; nt < 4; nt++) bbf[nt] = bfv[(wave * 4 + nt) * 16 + lr];
  f32x4 facc[3][4];
  #pragma unroll
  for (int mt = 0; mt < 3; mt++)
    #pragma unroll
    for (int nt = 0; nt < 4; nt++) facc[mt][nt] = (f32x4){0.f, 0.f, 0.f, 0.f};
  {
    f16x8 bvf[2][4];
    #pragma unroll
    for (int nt = 0; nt < 4; nt++)
      bvf[0][nt] = *(const f16x8*)&wfT[((wave * 4 + nt) * 16 + lr) * 256 + lq * 8];
    #pragma unroll
    for (int kk = 0; kk < 8; kk++) {
      if (kk < 7) {
        #pragma unroll
        for (int nt = 0; nt < 4; nt++)
          bvf[(kk + 1) & 1][nt] = *(const f16x8*)&wfT[((wave * 4 + nt) * 16 + lr) * 256
                                                      + (kk + 1) * 32 + lq * 8];
      }
      int k0 = kk * 32;
      int nband = k0 >> 6, noff = (k0 & 63) + lq * 8;   // 8-chunks stay in-band
      f16x8 av[3];
      #pragma unroll
      for (int mt = 0; mt < 3; mt++)
        av[mt] = *(const f16x8*)&qn[(mt * 16 + lr) * QP + 32 + nband * 96 + noff];
      #pragma unroll
      for (int nt = 0; nt < 4; nt++)
        #pragma unroll
        for (int mt = 0; mt < 3; mt++)
          facc[mt][nt] = mfma16(av[mt], bvf[kk & 1][nt], facc[mt][nt]);
    }
  }
  __syncthreads();   // all reads of n done; K/V bands may be overwritten below

  // ---- P7: add bf, LN2 partial stats (nWf part), write nWf over K/V bands ----
  {
    float vreg[3][4][4];
    #pragma unroll
    for (int nt = 0; nt < 4; nt++) {
      #pragma unroll
      for (int mt = 0; mt < 3; mt++)
        #pragma unroll
        for (int rg = 0; rg < 4; rg++) vreg[mt][nt][rg] = facc[mt][nt][rg] + bbf[nt];
    }
    #pragma unroll
    for (int mt = 0; mt < 3; mt++)
      #pragma unroll
      for (int rg = 0; rg < 4; rg++) {
        float s = 0.f, ss = 0.f;
        #pragma unroll
        for (int nt = 0; nt < 4; nt++) { float v = vreg[mt][nt][rg]; s += v; ss += v * v; }
        #pragma unroll
        for (int off = 1; off < 16; off <<= 1) {
          s += __shfl_xor(s, off, 64);
          ss += __shfl_xor(ss, off, 64);
        }
        if (lr == 0) {
          int r = mt * 16 + lq * 4 + rg;
          atomicAdd(&sum2[r], s);
          atomicAdd(&sq2[r], ss);
        }
      }
    #pragma unroll
    for (int mt = 0; mt < 3; mt++)
      #pragma unroll
      for (int nt = 0; nt < 4; nt++) {
        int c = (wave * 4 + nt) * 16 + lr;
        int cb = 32 + (c >> 6) * 96 + (c & 63);
        #pragma unroll
        for (int rg = 0; rg < 4; rg++) {
          int r = mt * 16 + lq * 4 + rg;
          qn[r * QP + cb] = (f16)vreg[mt][nt][rg];
        }
      }
  }
  // P8 affine params: cols (t&31)*16 per-thread constant -> hoist loads here
  // so latency hides behind the stats barrier.
  float g2v[16], b2v[16];
  {
    const int c8 = (t & 31) * 16;
    #pragma unroll
    for (int u = 0; u < 4; u++) {
      float4 a = *(const float4*)(g2 + c8 + u * 4);
      float4 b = *(const float4*)(be2 + c8 + u * 4);
      g2v[u*4+0]=a.x; g2v[u*4+1]=a.y; g2v[u*4+2]=a.z; g2v[u*4+3]=a.w;
      b2v[u*4+0]=b.x; b2v[u*4+1]=b.y; b2v[u*4+2]=b.z; b2v[u*4+3]=b.w;
    }
  }
  __syncthreads();
  if (t < SR) {
    float s = sum2[t] + sum1[t];          // m-part stats reused from LN1 raw sums
    float ss = sq2[t] + sq1[t];
    float mu = s * (1.f / 512.f);
    float var = ss * (1.f / 512.f) - mu * mu;
    mu2[t] = mu; rs2[t] = rsqrtf(var + 1e-5f);
  }
  __syncthreads();

  // ---- P8: write f_norm = LN2([nWf | x | attn])*g2+be2 -> fbuf (f16) ----
  {
    f16* fout = fbuf + (size_t)b0r * 3072;
    const int c0 = (t & 31) * 16;         // per-thread constant cols
    #pragma unroll
    for (int it = 0; it < 6; it++) {
      int i = t + it * 256;               // 0..1535
      int r = i >> 5;
      float mu = mu2[r], rs = rs2[r];
      const f16* src = (c0 < 256)
          ? &qn[r * QP + 32 + (c0 >> 6) * 96 + (c0 & 63)]                 // nWf bands
          : (c0 < 384)
          ? &xs[r * XP + (c0 - 256)]                                       // x
          : &qn[r * QP + ((c0 - 384) >> 5) * 96 + ((c0 - 384) & 31)];      // attn (Q bands)
      f16x8 ov[2];
      #pragma unroll
      for (int u = 0; u < 2; u++) {
        f16x8 v = ((const f16x8*)src)[u];
        #pragma unroll
        for (int e = 0; e < 8; e++) {
          int idx = u * 8 + e;
          ov[u][e] = (f16)(((float)v[e] - mu) * rs * g2v[idx] + b2v[idx]);
        }
      }
      f16x8* dst = (f16x8*)(fout + (size_t)r * 512 + c0);
      dst[0] = ov[0]; dst[1] = ov[1];
    }
  }
}

// ---------------- K2: out = relu(f @ Ws + bs)  (M=65536 K=3072 N=256) ----------------
// 128x256 tile, BK=32, 8 waves (2M x 4N), LDS 48 KB -> grid 512 = 2 blocks/CU
// so one block's barrier drain overlaps the other's compute. A fetched once;
// B (1.5 MB) stays L2-hot. XOR-swizzled fragments via pre-swizzled global src.
__global__ __launch_bounds__(512, 4) void k2_gemm(
    const f16* __restrict__ A, const f16* __restrict__ Bt,
    const float* __restrict__ bs, float* __restrict__ out)
{
  __shared__ __align__(16) f16 As[2 * 128 * 32];   // 16 KB
  __shared__ __align__(16) f16 Bs[2 * 256 * 32];   // 32 KB
  const int t = threadIdx.x;                // 0..511
  const int l = t & 63, w = t >> 6;         // lane, wave (8 waves)
  const int lr = l & 15, lq = l >> 4;       // lq = k-chunk 0..3
  const int wm = w >> 2, wn = w & 3;        // 2 x 4 wave grid
  const size_t m0 = (size_t)blockIdx.x * 128;

  // staging: per GLD16 a wave writes 1 KB = 16 rows x 64 B, linear in LDS.
  // lane l covers (row = base + (l>>2), physical chunk = l&3); logical chunk
  // there is (l&3) ^ (row&3).
  const int srow = l >> 2;                  // 0..15
  const int schk = (l & 3) ^ (srow & 3);
  const f16* ag  = A  + (m0 + w * 16 + srow) * 3072 + schk * 8;
  const f16* bg0 = Bt + (size_t)(w * 32 + srow) * 3072 + schk * 8;
  const f16* bg1 = Bt + (size_t)(w * 32 + 16 + srow) * 3072 + schk * 8;
  f16* lA  = As + w * 512;                  // + buf*4096 (f16 units)
  f16* lB0 = Bs + w * 1024;                 // + buf*8192
  f16* lB1 = Bs + w * 1024 + 512;

  // fragment ds_read offsets (f16 units, without buffer term):
  // row*32 + ((lq ^ (row&3)) * 8)
  int aoff[4], boff[4];
  #pragma unroll
  for (int mt = 0; mt < 4; mt++) {
    int row = wm * 64 + mt * 16 + lr;
    aoff[mt] = row * 32 + ((lq ^ (row & 3)) * 8);
  }
  #pragma unroll
  for (int nt = 0; nt < 4; nt++) {
    int row = wn * 64 + nt * 16 + lr;
    boff[nt] = row * 32 + ((lq ^ (row & 3)) * 8);
  }

  f32x4 acc[4][4];
  #pragma unroll
  for (int mt = 0; mt < 4; mt++)
    #pragma unroll
    for (int nt = 0; nt < 4; nt++) acc[mt][nt] = (f32x4){0.f, 0.f, 0.f, 0.f};

  auto stage = [&](int buf, int tile) {
    GLD16(ag  + tile * 32, lA  + buf * 4096);
    GLD16(bg0 + tile * 32, lB0 + buf * 8192);
    GLD16(bg1 + tile * 32, lB1 + buf * 8192);
  };
  auto compute = [&](int buf) {
    f16x8 av[4], bv[4];
    #pragma unroll
    for (int nt = 0; nt < 4; nt++)
      bv[nt] = *(const f16x8*)&Bs[buf * 8192 + boff[nt]];
    #pragma unroll
    for (int mt = 0; mt < 4; mt++)
      av[mt] = *(const f16x8*)&As[buf * 4096 + aoff[mt]];
    #pragma unroll
    for (int mt = 0; mt < 4; mt++)
      #pragma unroll
      for (int nt = 0; nt < 4; nt++)
        acc[mt][nt] = mfma16(av[mt], bv[nt], acc[mt][nt]);
  };

  // K = 3072 -> 96 tiles of 32. Depth-1 pipeline, one barrier per tile.
  stage(0, 0);
  __syncthreads();                          // tile 0 ready
  #pragma unroll 1
  for (int kt = 0; kt < 96; kt += 2) {
    stage(1, kt + 1);                       // prefetch next tile (other buffer)
    compute(0);
    __syncthreads();                        // drains stage(1); buf0 reads done
    if (kt + 2 < 96) stage(0, kt + 2);
    compute(1);
    if (kt + 2 < 96) __syncthreads();       // drains stage(0); buf1 reads done
  }

  // epilogue: bias + relu, fp32 store
  #pragma unroll
  for (int nt = 0; nt < 4; nt++) {
    int col = wn * 64 + nt * 16 + lr;
    float bb = bs[col];
    #pragma unroll
    for (int mt = 0; mt < 4; mt++) {
      size_t rowb = m0 + wm * 64 + mt * 16 + lq * 4;
      #pragma unroll
      for (int rg = 0; rg < 4; rg++) {
        float v = acc[mt][nt][rg] + bb;
        out[(rowb + rg) * 256 + col] = v > 0.f ? v : 0.f;
      }
    }
  }
}

// ---------------- launch ----------------
extern "C" void kernel_launch(void* const* d_in, const int* in_sizes, int n_in,
                              void* d_out, int out_size, void* d_ws, size_t ws_size,
                              hipStream_t stream) {
  (void)in_sizes; (void)n_in; (void)out_size; (void)ws_size;
  const float* x   = (const float*)d_in[0];
  const float* W0  = (const float*)d_in[1];  const float* b0  = (const float*)d_in[2];
  const float* W1  = (const float*)d_in[3];  const float* b1  = (const float*)d_in[4];
  const float* W2  = (const float*)d_in[5];  const float* b2  = (const float*)d_in[6];
  const float* W3  = (const float*)d_in[7];  const float* b3  = (const float*)d_in[8];
  const float* g1  = (const float*)d_in[9];  const float* be1 = (const float*)d_in[10];
  const float* Wf  = (const float*)d_in[11]; const float* bf  = (const float*)d_in[12];
  const float* g2  = (const float*)d_in[13]; const float* be2 = (const float*)d_in[14];
  const float* Ws  = (const float*)d_in[15]; const float* bs  = (const float*)d_in[16];
  float* out = (float*)d_out;

  char* ws = (char*)d_ws;
  f16*   wqkvT = (f16*)(ws);                 //   98304 B  [384][128]
  f16*   wfT   = (f16*)(ws + 98304);         //  131072 B  [256][256]
  f16*   wsT   = (f16*)(ws + 229376);        // 1572864 B  [256][3072]
  float* bqkv  = (float*)(ws + 1802240);     //    1536 B
  f16*   fbuf  = (f16*)(ws + 1804288);       // 402653184 B [65536*6][512]

  k0_prep<<<3522, 256, 0, stream>>>(W0, b0, W1, b1, W2, b2, W3, b3, Wf, Ws,
                                    wqkvT, wfT, wsT, bqkv);
  k1_fused<<<8192, 256, 0, stream>>>(x, wqkvT, wfT, bqkv, g1, be1, bf, g2, be2, fbuf);
  k2_gemm<<<512, 512, 0, stream>>>(fbuf, wsT, bs, out);
}

// Round 6
// 723.177 us; speedup vs baseline: 1.0422x; 1.0422x over previous
//
#include <hip/hip_runtime.h>

typedef _Float16 f16;
typedef _Float16 f16x8 __attribute__((ext_vector_type(8)));
typedef float f32x4 __attribute__((ext_vector_type(4)));

static __device__ __forceinline__ f32x4 mfma16(f16x8 a, f16x8 b, f32x4 c) {
  return __builtin_amdgcn_mfma_f32_16x16x32_f16(a, b, c, 0, 0, 0);
}

#define GLD16(gp, lp) __builtin_amdgcn_global_load_lds( \
    (const __attribute__((address_space(1))) unsigned int*)(gp), \
    (__attribute__((address_space(3))) unsigned int*)(lp), 16, 0, 0)

// ---------------- K0: weight prep (fp32 -> f16, transposed to [n][k]) ----------------
__global__ __launch_bounds__(256) void k0_prep(
    const float* __restrict__ W0, const float* __restrict__ b0,
    const float* __restrict__ W1, const float* __restrict__ b1,
    const float* __restrict__ W2, const float* __restrict__ b2,
    const float* __restrict__ W3, const float* __restrict__ b3,
    const float* __restrict__ Wf, const float* __restrict__ Ws,
    f16* __restrict__ wqkvT, f16* __restrict__ wfT, f16* __restrict__ wsT,
    float* __restrict__ bqkv)
{
  int t = blockIdx.x * 256 + threadIdx.x;
  if (t < 49152) {                       // wqkvT [384][128], n = h*96 + j
    int n = t >> 7, k = t & 127;
    int h = n / 96, nn = n - h * 96;
    const float* W = (h == 0) ? W0 : (h == 1) ? W1 : (h == 2) ? W2 : W3;
    wqkvT[t] = (f16)W[k * 96 + nn];
  } else if (t < 114688) {               // wfT [256][256]
    int i = t - 49152;
    int n = i >> 8, k = i & 255;
    wfT[i] = (f16)Wf[k * 256 + n];
  } else if (t < 901120) {               // wsT [256][3072]
    int i = t - 114688;
    int n = i / 3072, k = i - n * 3072;
    wsT[i] = (f16)Ws[k * 256 + n];
  } else if (t < 901504) {               // bqkv [384] fp32
    int i = t - 901120;
    int h = i / 96, j = i - h * 96;
    const float* bp = (h == 0) ? b0 : (h == 1) ? b1 : (h == 2) ? b2 : b3;
    bqkv[i] = bp[j];
  }
}

// ---------------- K1: fused qkv + attention + LN1 + Wf + LN2 -> f_norm (f16) ----------------
// (unchanged from round 5: 371 us, 3 blocks/CU, reg-dbuf weight loads)
#define RB 8            // batch rows per block
#define SR 48           // seq rows = RB*6
#define XP 136          // f16 pitch for 128-col x tile
#define QP 392          // f16 pitch for qkv (384 cols)

__global__ __launch_bounds__(256, 3) void k1_fused(
    const float* __restrict__ x,
    const f16* __restrict__ wqkvT, const f16* __restrict__ wfT,
    const float* __restrict__ bqkv,
    const float* __restrict__ g1, const float* __restrict__ be1,
    const float* __restrict__ bfv,
    const float* __restrict__ g2, const float* __restrict__ be2,
    f16* __restrict__ fbuf)
{
  __shared__ f16 xs[SR * XP];       // x tile (m cols 0..127 / f cols 256..383)
  __shared__ f16 qn[SR * QP];       // qkv; Q cols -> attn; K/V bands -> n -> nWf
  __shared__ float sum1[SR], sq1[SR], mu1[SR], rs1[SR];
  __shared__ float sum2[SR], sq2[SR], mu2[SR], rs2[SR];

  const int t = threadIdx.x;
  const int lane = t & 63, wave = t >> 6;   // 4 waves
  const int lr = lane & 15, lq = lane >> 4;
  const int b0r = blockIdx.x * RB;

  // ---- P0: stat zeroing ----
  if (t < SR) { sum1[t] = 0.f; sq1[t] = 0.f; sum2[t] = 0.f; sq2[t] = 0.f; }

  // ---- P1: load x -> xs (f16) ----
  {
    const float4* xg = (const float4*)(x + (size_t)b0r * 768);
    #pragma unroll
    for (int it = 0; it < 6; it++) {
      int i = t + it * 256;               // 0..1535 ; 32 float4 per row
      float4 v = xg[i];
      int r = i >> 5, c4 = i & 31;
      f16* d = &xs[r * XP + c4 * 4];
      d[0] = (f16)v.x; d[1] = (f16)v.y; d[2] = (f16)v.z; d[3] = (f16)v.w;
    }
  }
  __syncthreads();

  // ---- P2: qkv = x @ Wqkv + b  (MFMA M=48 N=384 K=128; B-frags reg-dbuf) ----
  {
    float bb[6];
    #pragma unroll
    for (int nt = 0; nt < 6; nt++) bb[nt] = bqkv[(wave * 6 + nt) * 16 + lr];
    f32x4 acc[3][6];
    #pragma unroll
    for (int mt = 0; mt < 3; mt++)
      #pragma unroll
      for (int nt = 0; nt < 6; nt++) acc[mt][nt] = (f32x4){0.f, 0.f, 0.f, 0.f};
    f16x8 bv[2][6];
    #pragma unroll
    for (int nt = 0; nt < 6; nt++)
      bv[0][nt] = *(const f16x8*)&wqkvT[((wave * 6 + nt) * 16 + lr) * 128 + lq * 8];
    #pragma unroll
    for (int kk = 0; kk < 4; kk++) {
      if (kk < 3) {
        #pragma unroll
        for (int nt = 0; nt < 6; nt++)
          bv[(kk + 1) & 1][nt] = *(const f16x8*)&wqkvT[((wave * 6 + nt) * 16 + lr) * 128
                                                       + (kk + 1) * 32 + lq * 8];
      }
      f16x8 av[3];
      #pragma unroll
      for (int mt = 0; mt < 3; mt++)
        av[mt] = *(const f16x8*)&xs[(mt * 16 + lr) * XP + kk * 32 + lq * 8];
      #pragma unroll
      for (int nt = 0; nt < 6; nt++)
        #pragma unroll
        for (int mt = 0; mt < 3; mt++)
          acc[mt][nt] = mfma16(av[mt], bv[kk & 1][nt], acc[mt][nt]);
    }
    #pragma unroll
    for (int nt = 0; nt < 6; nt++) {
      int c = (wave * 6 + nt) * 16 + lr;
      #pragma unroll
      for (int mt = 0; mt < 3; mt++) {
        #pragma unroll
        for (int rg = 0; rg < 4; rg++) {
          int r = mt * 16 + lq * 4 + rg;
          qn[r * QP + c] = (f16)(acc[mt][nt][rg] + bb[nt]);
        }
      }
    }
  }
  __syncthreads();

  // ---- P3: attention (VALU, fp32 accumulate). thread = (b, h, i). ----
  if (t < 192) {
    int b = t / 24;
    int rem = t - b * 24;
    int h = rem / 6, i = rem - (rem / 6) * 6;
    const f16* base = &qn[(b * 6) * QP + h * 96];
    float q[32], o[32], s[6];
    {
      const f16x8* Qr = (const f16x8*)(base + i * QP);
      #pragma unroll
      for (int u = 0; u < 4; u++) {
        f16x8 v = Qr[u];
        #pragma unroll
        for (int e = 0; e < 8; e++) q[u * 8 + e] = (float)v[e];
      }
    }
    #pragma unroll
    for (int j = 0; j < 6; j++) {
      const f16x8* Kr = (const f16x8*)(base + j * QP + 32);
      float a = 0.f;
      #pragma unroll
      for (int u = 0; u < 4; u++) {
        f16x8 v = Kr[u];
        #pragma unroll
        for (int e = 0; e < 8; e++) a += q[u * 8 + e] * (float)v[e];
      }
      s[j] = a;
    }
    #pragma unroll
    for (int d = 0; d < 32; d++) o[d] = 0.f;
    #pragma unroll
    for (int j = 0; j < 6; j++) {
      const f16x8* Vr = (const f16x8*)(base + j * QP + 64);
      float sj = s[j];
      #pragma unroll
      for (int u = 0; u < 4; u++) {
        f16x8 v = Vr[u];
        #pragma unroll
        for (int e = 0; e < 8; e++) o[u * 8 + e] += sj * (float)v[e];
      }
    }
    f16x8* Ar = (f16x8*)&qn[(b * 6 + i) * QP + h * 96];   // overwrite own Q band
    #pragma unroll
    for (int u = 0; u < 4; u++) {
      f16x8 v;
      #pragma unroll
      for (int e = 0; e < 8; e++) v[e] = (f16)o[u * 8 + e];
      Ar[u] = v;
    }
  }
  __syncthreads();

  // ---- P4: LN1 stats over m = [xs | attn(Q bands)] (256 cols) ----
  float g1v[16], b1v[16];
  {
    const int c5 = (t & 15) * 16;
    #pragma unroll
    for (int u = 0; u < 4; u++) {
      float4 a = *(const float4*)(g1 + c5 + u * 4);
      float4 b = *(const float4*)(be1 + c5 + u * 4);
      g1v[u*4+0]=a.x; g1v[u*4+1]=a.y; g1v[u*4+2]=a.z; g1v[u*4+3]=a.w;
      b1v[u*4+0]=b.x; b1v[u*4+1]=b.y; b1v[u*4+2]=b.z; b1v[u*4+3]=b.w;
    }
  }
  if (t < 192) {
    int r = t >> 2, qq = t & 3;
    float s = 0.f, ss = 0.f;
    if (qq < 2) {
      const f16x8* src = (const f16x8*)&xs[r * XP + qq * 64];
      #pragma unroll
      for (int u = 0; u < 8; u++) {
        f16x8 v = src[u];
        #pragma unroll
        for (int e = 0; e < 8; e++) { float f = (float)v[e]; s += f; ss += f * f; }
      }
    } else {
      int h0 = (qq - 2) * 2;              // heads h0, h0+1 (32 cols each)
      const f16x8* s0 = (const f16x8*)&qn[r * QP + h0 * 96];
      const f16x8* s1 = (const f16x8*)&qn[r * QP + (h0 + 1) * 96];
      #pragma unroll
      for (int u = 0; u < 4; u++) {
        f16x8 v = s0[u];
        #pragma unroll
        for (int e = 0; e < 8; e++) { float f = (float)v[e]; s += f; ss += f * f; }
      }
      #pragma unroll
      for (int u = 0; u < 4; u++) {
        f16x8 v = s1[u];
        #pragma unroll
        for (int e = 0; e < 8; e++) { float f = (float)v[e]; s += f; ss += f * f; }
      }
    }
    atomicAdd(&sum1[r], s);
    atomicAdd(&sq1[r], ss);
  }
  __syncthreads();
  if (t < SR) {
    float mu = sum1[t] * (1.f / 256.f);
    float var = sq1[t] * (1.f / 256.f) - mu * mu;
    mu1[t] = mu; rs1[t] = rsqrtf(var + 1e-5f);
  }
  __syncthreads();

  // ---- P5: n = LN1(m)*g1+be1 -> K/V bands of qn (band = c0>>6, at 32+band*96) ----
  {
    const int c0 = (t & 15) * 16;         // per-thread constant cols
    #pragma unroll
    for (int it = 0; it < 3; it++) {
      int i = t + it * 256;               // 0..767
      int r = i >> 4;
      float mu = mu1[r], rs = rs1[r];
      const f16* src = (c0 < 128)
          ? &xs[r * XP + c0]
          : &qn[r * QP + ((c0 - 128) >> 5) * 96 + ((c0 - 128) & 31)];
      f16x8 ov[2];
      #pragma unroll
      for (int u = 0; u < 2; u++) {
        f16x8 v = ((const f16x8*)src)[u];
        #pragma unroll
        for (int e = 0; e < 8; e++) {
          int idx = u * 8 + e;
          ov[u][e] = (f16)(((float)v[e] - mu) * rs * g1v[idx] + b1v[idx]);
        }
      }
      f16x8* dst = (f16x8*)&qn[r * QP + 32 + (c0 >> 6) * 96 + (c0 & 63)];
      dst[0] = ov[0]; dst[1] = ov[1];
    }
  }
  __syncthreads();

  // ---- P6: nWf = n @ Wf (MFMA M=48 N=256 K=256; B-frags reg-dbuf) ----
  float bbf[4];
  #pragma unroll
  for (int nt = 0; nt < 4; nt++) bbf[nt] = bfv[(wave * 4 + nt) * 16 + lr];
  f32x4 facc[3][4];
  #pragma unroll
  for (int mt = 0; mt < 3; mt++)
    #pragma unroll
    for (int nt = 0; nt < 4; nt++) facc[mt][nt] = (f32x4){0.f, 0.f, 0.f, 0.f};
  {
    f16x8 bvf[2][4];
    #pragma unroll
    for (int nt = 0; nt < 4; nt++)
      bvf[0][nt] = *(const f16x8*)&wfT[((wave * 4 + nt) * 16 + lr) * 256 + lq * 8];
    #pragma unroll
    for (int kk = 0; kk < 8; kk++) {
      if (kk < 7) {
        #pragma unroll
        for (int nt = 0; nt < 4; nt++)
          bvf[(kk + 1) & 1][nt] = *(const f16x8*)&wfT[((wave * 4 + nt) * 16 + lr) * 256
                                                      + (kk + 1) * 32 + lq * 8];
      }
      int k0 = kk * 32;
      int nband = k0 >> 6, noff = (k0 & 63) + lq * 8;   // 8-chunks stay in-band
      f16x8 av[3];
      #pragma unroll
      for (int mt = 0; mt < 3; mt++)
        av[mt] = *(const f16x8*)&qn[(mt * 16 + lr) * QP + 32 + nband * 96 + noff];
      #pragma unroll
      for (int nt = 0; nt < 4; nt++)
        #pragma unroll
        for (int mt = 0; mt < 3; mt++)
          facc[mt][nt] = mfma16(av[mt], bvf[kk & 1][nt], facc[mt][nt]);
    }
  }
  __syncthreads();   // all reads of n done; K/V bands may be overwritten below

  // ---- P7: add bf, LN2 partial stats (nWf part), write nWf over K/V bands ----
  {
    float vreg[3][4][4];
    #pragma unroll
    for (int nt = 0; nt < 4; nt++) {
      #pragma unroll
      for (int mt = 0; mt < 3; mt++)
        #pragma unroll
        for (int rg = 0; rg < 4; rg++) vreg[mt][nt][rg] = facc[mt][nt][rg] + bbf[nt];
    }
    #pragma unroll
    for (int mt = 0; mt < 3; mt++)
      #pragma unroll
      for (int rg = 0; rg < 4; rg++) {
        float s = 0.f, ss = 0.f;
        #pragma unroll
        for (int nt = 0; nt < 4; nt++) { float v = vreg[mt][nt][rg]; s += v; ss += v * v; }
        #pragma unroll
        for (int off = 1; off < 16; off <<= 1) {
          s += __shfl_xor(s, off, 64);
          ss += __shfl_xor(ss, off, 64);
        }
        if (lr == 0) {
          int r = mt * 16 + lq * 4 + rg;
          atomicAdd(&sum2[r], s);
          atomicAdd(&sq2[r], ss);
        }
      }
    #pragma unroll
    for (int mt = 0; mt < 3; mt++)
      #pragma unroll
      for (int nt = 0; nt < 4; nt++) {
        int c = (wave * 4 + nt) * 16 + lr;
        int cb = 32 + (c >> 6) * 96 + (c & 63);
        #pragma unroll
        for (int rg = 0; rg < 4; rg++) {
          int r = mt * 16 + lq * 4 + rg;
          qn[r * QP + cb] = (f16)vreg[mt][nt][rg];
        }
      }
  }
  float g2v[16], b2v[16];
  {
    const int c8 = (t & 31) * 16;
    #pragma unroll
    for (int u = 0; u < 4; u++) {
      float4 a = *(const float4*)(g2 + c8 + u * 4);
      float4 b = *(const float4*)(be2 + c8 + u * 4);
      g2v[u*4+0]=a.x; g2v[u*4+1]=a.y; g2v[u*4+2]=a.z; g2v[u*4+3]=a.w;
      b2v[u*4+0]=b.x; b2v[u*4+1]=b.y; b2v[u*4+2]=b.z; b2v[u*4+3]=b.w;
    }
  }
  __syncthreads();
  if (t < SR) {
    float s = sum2[t] + sum1[t];          // m-part stats reused from LN1 raw sums
    float ss = sq2[t] + sq1[t];
    float mu = s * (1.f / 512.f);
    float var = ss * (1.f / 512.f) - mu * mu;
    mu2[t] = mu; rs2[t] = rsqrtf(var + 1e-5f);
  }
  __syncthreads();

  // ---- P8: write f_norm = LN2([nWf | x | attn])*g2+be2 -> fbuf (f16) ----
  {
    f16* fout = fbuf + (size_t)b0r * 3072;
    const int c0 = (t & 31) * 16;         // per-thread constant cols
    #pragma unroll
    for (int it = 0; it < 6; it++) {
      int i = t + it * 256;               // 0..1535
      int r = i >> 5;
      float mu = mu2[r], rs = rs2[r];
      const f16* src = (c0 < 256)
          ? &qn[r * QP + 32 + (c0 >> 6) * 96 + (c0 & 63)]                 // nWf bands
          : (c0 < 384)
          ? &xs[r * XP + (c0 - 256)]                                       // x
          : &qn[r * QP + ((c0 - 384) >> 5) * 96 + ((c0 - 384) & 31)];      // attn (Q bands)
      f16x8 ov[2];
      #pragma unroll
      for (int u = 0; u < 2; u++) {
        f16x8 v = ((const f16x8*)src)[u];
        #pragma unroll
        for (int e = 0; e < 8; e++) {
          int idx = u * 8 + e;
          ov[u][e] = (f16)(((float)v[e] - mu) * rs * g2v[idx] + b2v[idx]);
        }
      }
      f16x8* dst = (f16x8*)(fout + (size_t)r * 512 + c0);
      dst[0] = ov[0]; dst[1] = ov[1];
    }
  }
}

// ---------------- K2: out = relu(f @ Ws + bs)  (M=65536 K=3072 N=256) ----------------
// 256x256 tile, BK=64, 8 waves (2M x 4N), double-buffered LDS. Counted-vmcnt
// pipeline (T4): raw s_barrier + s_waitcnt vmcnt(8) keeps next tile's 8 loads
// per wave in flight ACROSS the barrier (no vmcnt(0) drain in the main loop).
// Hazards: RAW -- each wave issues exactly 8 GLD16/stage, so vmcnt(8) means
// the previous tile's loads landed; barrier extends that to all waves.
// WAR -- a buffer is re-staged only after the post-compute barrier, so all
// reads completed before any overwriting DMA is issued.
__global__ __launch_bounds__(512, 2) void k2_gemm(
    const f16* __restrict__ A, const f16* __restrict__ Bt,
    const float* __restrict__ bs, float* __restrict__ out)
{
  __shared__ __align__(16) f16 As[2 * 256 * 64];   // [buf][row 256][chunk 8][8 f16]
  __shared__ __align__(16) f16 Bs[2 * 256 * 64];
  const int t = threadIdx.x;                // 0..511
  const int l = t & 63, w = t >> 6;         // lane, wave (8 waves)
  const int lr = l & 15, lq = l >> 4;
  const int wm = w >> 2, wn = w & 3;        // 2 x 4 wave grid
  const size_t m0 = (size_t)blockIdx.x * 256;

  // staging: per GLD16 a wave writes 1024 B = 8 rows x 128 B, linear in LDS.
  // lane l covers (row = base + (l>>3), physical chunk = l&7); the logical
  // k-chunk that belongs there is (l&7) ^ (row&7) = (l&7) ^ (l>>3).
  const int srow = l >> 3;
  const int schk = (l & 7) ^ srow;
  const f16* ap[4]; const f16* bp[4];
  #pragma unroll
  for (int i = 0; i < 4; i++) {
    int r = w * 32 + i * 8 + srow;          // rows 0..255 across 8 waves x 4 issues
    ap[i] = A  + (m0 + r) * 3072 + schk * 8;
    bp[i] = Bt + (size_t)r * 3072 + schk * 8;
  }

  // fragment ds_read offsets (f16 units, without buffer term):
  // row*64 + ((kchunk ^ (row&7)) * 8), kchunk = kk*4 + lq
  int aoff[8][2], boff[4][2];
  #pragma unroll
  for (int mt = 0; mt < 8; mt++)
    #pragma unroll
    for (int kk = 0; kk < 2; kk++) {
      int row = wm * 128 + mt * 16 + lr;
      aoff[mt][kk] = row * 64 + (((kk * 4 + lq) ^ (row & 7)) * 8);
    }
  #pragma unroll
  for (int nt = 0; nt < 4; nt++)
    #pragma unroll
    for (int kk = 0; kk < 2; kk++) {
      int row = wn * 64 + nt * 16 + lr;
      boff[nt][kk] = row * 64 + (((kk * 4 + lq) ^ (row & 7)) * 8);
    }

  f32x4 acc[8][4];
  #pragma unroll
  for (int mt = 0; mt < 8; mt++)
    #pragma unroll
    for (int nt = 0; nt < 4; nt++) acc[mt][nt] = (f32x4){0.f, 0.f, 0.f, 0.f};

  auto stage = [&](int buf, int tile) {     // 8 GLD16 per thread (wave: 8 vmem ops)
    #pragma unroll
    for (int i = 0; i < 4; i++) {
      GLD16(ap[i] + tile * 64, As + buf * 16384 + w * 2048 + i * 512);
      GLD16(bp[i] + tile * 64, Bs + buf * 16384 + w * 2048 + i * 512);
    }
  };
  auto compute = [&](int buf) {
    #pragma unroll
    for (int kk = 0; kk < 2; kk++) {
      f16x8 av[8], bv[4];
      #pragma unroll
      for (int nt = 0; nt < 4; nt++)
        bv[nt] = *(const f16x8*)&Bs[buf * 16384 + boff[nt][kk]];
      #pragma unroll
      for (int mt = 0; mt < 8; mt++)
        av[mt] = *(const f16x8*)&As[buf * 16384 + aoff[mt][kk]];
      #pragma unroll
      for (int mt = 0; mt < 8; mt++)
        #pragma unroll
        for (int nt = 0; nt < 4; nt++)
          acc[mt][nt] = mfma16(av[mt], bv[nt], acc[mt][nt]);
    }
  };

  // K = 3072 -> 48 tiles of 64. Counted-vmcnt pipeline, depth 1.
  stage(0, 0);
  #pragma unroll 1
  for (int kt = 0; kt < 48; ++kt) {
    int cur = kt & 1;
    if (kt + 1 < 48) {
      stage(cur ^ 1, kt + 1);               // issue next tile; 16 outstanding
      asm volatile("s_waitcnt vmcnt(8)" ::: "memory");   // oldest 8 (tile kt) done
    } else {
      asm volatile("s_waitcnt vmcnt(0)" ::: "memory");   // tail: drain last tile
    }
    __builtin_amdgcn_s_barrier();           // tile kt visible to all waves
    compute(cur);
    __builtin_amdgcn_s_barrier();           // all reads of buf cur done -> re-stageable
  }

  // epilogue: bias + relu, fp32 store
  #pragma unroll
  for (int nt = 0; nt < 4; nt++) {
    int col = wn * 64 + nt * 16 + lr;
    float bb = bs[col];
    #pragma unroll
    for (int mt = 0; mt < 8; mt++) {
      size_t rowb = m0 + wm * 128 + mt * 16 + lq * 4;
      #pragma unroll
      for (int rg = 0; rg < 4; rg++) {
        float v = acc[mt][nt][rg] + bb;
        out[(rowb + rg) * 256 + col] = v > 0.f ? v : 0.f;
      }
    }
  }
}

// ---------------- launch ----------------
extern "C" void kernel_launch(void* const* d_in, const int* in_sizes, int n_in,
                              void* d_out, int out_size, void* d_ws, size_t ws_size,
                              hipStream_t stream) {
  (void)in_sizes; (void)n_in; (void)out_size; (void)ws_size;
  const float* x   = (const float*)d_in[0];
  const float* W0  = (const float*)d_in[1];  const float* b0  = (const float*)d_in[2];
  const float* W1  = (const float*)d_in[3];  const float* b1  = (const float*)d_in[4];
  const float* W2  = (const float*)d_in[5];  const float* b2  = (const float*)d_in[6];
  const float* W3  = (const float*)d_in[7];  const float* b3  = (const float*)d_in[8];
  const float* g1  = (const float*)d_in[9];  const float* be1 = (const float*)d_in[10];
  const float* Wf  = (const float*)d_in[11]; const float* bf  = (const float*)d_in[12];
  const float* g2  = (const float*)d_in[13]; const float* be2 = (const float*)d_in[14];
  const float* Ws  = (const float*)d_in[15]; const float* bs  = (const float*)d_in[16];
  float* out = (float*)d_out;

  char* ws = (char*)d_ws;
  f16*   wqkvT = (f16*)(ws);                 //   98304 B  [384][128]
  f16*   wfT   = (f16*)(ws + 98304);         //  131072 B  [256][256]
  f16*   wsT   = (f16*)(ws + 229376);        // 1572864 B  [256][3072]
  float* bqkv  = (float*)(ws + 1802240);     //    1536 B
  f16*   fbuf  = (f16*)(ws + 1804288);       // 402653184 B [65536*6][512]

  k0_prep<<<3522, 256, 0, stream>>>(W0, b0, W1, b1, W2, b2, W3, b3, Wf, Ws,
                                    wqkvT, wfT, wsT, bqkv);
  k1_fused<<<8192, 256, 0, stream>>>(x, wqkvT, wfT, bqkv, g1, be1, bf, g2, be2, fbuf);
  k2_gemm<<<256, 512, 0, stream>>>(fbuf, wsT, bs, out);
}